// Round 8
// baseline (225.177 us; speedup 1.0000x reference)
//
#include <hip/hip_runtime.h>
#include <stdint.h>

typedef short short8 __attribute__((ext_vector_type(8)));
typedef float f32x4 __attribute__((ext_vector_type(4)));
typedef unsigned short u16;
typedef unsigned int u32;

struct alignas(8) U16x4 { u16 x, y, z, w; };

__device__ __forceinline__ u16 f2bf(float f) {
  u32 u = __float_as_uint(f);
  u += 0x7fffu + ((u >> 16) & 1u);
  return (u16)(u >> 16);
}
__device__ __forceinline__ float bf2f(u16 v) {
  return __uint_as_float(((u32)v) << 16);
}

__device__ __forceinline__ void gld_lds16(const u16* g, u16* l) {
  __builtin_amdgcn_global_load_lds((const __attribute__((address_space(1))) u32*)g,
                                   (__attribute__((address_space(3))) u32*)l,
                                   16, 0, 0);
}

__device__ __forceinline__ void mfma16x16x32(f32x4& c, short8 a, short8 b) {
  asm("v_mfma_f32_16x16x32_bf16 %0, %1, %2, %0" : "+v"(c) : "v"(a), "v"(b));
}

__device__ __forceinline__ float wave_red(float v) {
  for (int off = 32; off; off >>= 1) v += __shfl_down(v, off);
  return v;
}

// ---------------------------------------------------------------------------
// Batched C = A * B^T (A:[M,K] rm, Bt:[N,K] rm). BM=256 x BN=128 x BK=32,
// 512 threads / 8 waves (4x2, wave tile 64x64, acc[4][4]). Taller tile cuts
// staged bytes/FLOP by 25% vs 128^2 (the measured bottleneck: ~8 B/cyc/CU
// staging port, 4000 cyc per 128^2 iter). LDS 48 KB static, double-buffered,
// counted vmcnt(3) pipeline (3 gld_lds/thread/iter).
// T2: XOR-swizzle (16B chunk ^= row&3); linear LDS dest, pre-swizzled global
//     source (rule #21). Residual 4-way frag-read conflict accepted (ds pipe
//     has ~2x headroom vs staging).
// T1: flat grids decoded so batch b lives on XCD b%8.
// EPI 0: bf16 out; EPI 6: bf16 + v1[b512+row]*v2[col] + v3[row]*v4[b512+col];
// EPI 4: f32 out, acc*v1[row] + v2[b512+row] + bf16 xres[b][row][col]
// ---------------------------------------------------------------------------
template<int EPI>
__global__ void __launch_bounds__(512, 2) gemm_abt(
                         const u16* __restrict__ A, int64_t Abs,
                         const u16* __restrict__ Bt, int64_t Bbs,
                         void* __restrict__ Cptr, int64_t Cbs,
                         int M, int N, int K,
                         const float* __restrict__ v1,
                         const float* __restrict__ v2,
                         const float* __restrict__ v3,
                         const float* __restrict__ v4,
                         const u16* __restrict__ xres) {
  constexpr int BM = 256, BN = 128, BK = 32;
  __shared__ u16 As[2][BM * BK];   // 32 KB
  __shared__ u16 Bs[2][BN * BK];   // 16 KB

  int bx, by, b;
  if (gridDim.z == 1) {            // T1: XCD-aware flat decode
    const int nbx = N >> 7;
    const int bpb = nbx * (M >> 8);
    const int id = blockIdx.x;
    const int xcd = id & 7, rest = id >> 3;
    b = xcd + 8 * (rest / bpb);
    const int wi = rest % bpb;
    by = wi / nbx; bx = wi % nbx;
  } else {
    bx = blockIdx.x; by = blockIdx.y; b = blockIdx.z;
  }

  const u16* Ab = A + (int64_t)b * Abs;
  const u16* Bb = Bt + (int64_t)b * Bbs;
  const int brow = by * BM, bcol = bx * BN;
  const int tid = threadIdx.x, lane = tid & 63, w = tid >> 6;
  const int wr = w >> 1, wc = w & 1;  // 4x2 wave grid; wave tile 64x64

  f32x4 acc[4][4] = {};

  // staging: thread t -> row sr=t>>2 (A also sr+128), 8-elem chunk t&3.
  // LDS dest LINEAR (wave base + lane*16B); global chunk pre-swizzled ^(row&3).
  const int sr = tid >> 2;           // 0..127
  const int scs = ((tid & 3) ^ (sr & 3)) * 8;
  u16* lA0 = &As[0][sr * BK + (tid & 3) * 8];
  u16* lB0 = &Bs[0][sr * BK + (tid & 3) * 8];
  const u16* gA = Ab + (int64_t)(brow + sr) * K + scs;
  const u16* gB = Bb + (int64_t)(bcol + sr) * K + scs;

  const int la16 = lane & 15;
  const int kg = (lane >> 4) * 8;            // k-granule 0/8/16/24
  const int kc = kg ^ ((la16 & 3) * 8);      // swizzled ds_read chunk
  const int nt = K / BK;

  // prologue: stage tile 0 into buf 0
  gld_lds16(gA, lA0);
  gld_lds16(gA + (int64_t)128 * K, lA0 + 128 * BK);
  gld_lds16(gB, lB0);

  for (int t = 0; t < nt; ++t) {
    __builtin_amdgcn_s_barrier();  // prev iter's LDS reads done before overwrite
    if (t + 1 < nt) {
      const int nb = (t + 1) & 1;
      const int k0 = (t + 1) * BK;
      u16* la = lA0 + nb * BM * BK;
      u16* lb = lB0 + nb * BN * BK;
      gld_lds16(gA + k0, la);
      gld_lds16(gA + (int64_t)128 * K + k0, la + 128 * BK);
      gld_lds16(gB + k0, lb);
      asm volatile("s_waitcnt vmcnt(3)" ::: "memory");  // tile t landed; next in flight
    } else {
      asm volatile("s_waitcnt vmcnt(0)" ::: "memory");
    }
    __builtin_amdgcn_s_barrier();
    __builtin_amdgcn_sched_barrier(0);
    const u16* as = As[t & 1];
    const u16* bs = Bs[t & 1];
    short8 af[4], bf[4];
#pragma unroll
    for (int m = 0; m < 4; ++m)
      af[m] = *(const short8*)&as[(wr * 64 + m * 16 + la16) * BK + kc];
#pragma unroll
    for (int n = 0; n < 4; ++n)
      bf[n] = *(const short8*)&bs[(wc * 64 + n * 16 + la16) * BK + kc];
#pragma unroll
    for (int m = 0; m < 4; ++m)
#pragma unroll
      for (int n = 0; n < 4; ++n)
        mfma16x16x32(acc[m][n], af[m], bf[n]);
  }
  asm volatile("s_nop 7\n\ts_nop 7");  // MFMA->VALU hazard guard

  const int r0 = brow + wr * 64 + (lane >> 4) * 4;
  const int c0 = bcol + wc * 64 + la16;
  const int64_t b512 = (int64_t)b * 512;

  if (EPI == 4) {
    float* Cb = (float*)Cptr + (int64_t)b * Cbs;
    const u16* xb = xres + (int64_t)b * Cbs;
#pragma unroll
    for (int m = 0; m < 4; ++m) {
#pragma unroll
      for (int r = 0; r < 4; ++r) {
        const int row = r0 + m * 16 + r;
        const float scl = v1[row], shf = v2[b512 + row];
#pragma unroll
        for (int n = 0; n < 4; ++n) {
          const int col = c0 + n * 16;
          Cb[(int64_t)row * N + col] =
              acc[m][n][r] * scl + shf + bf2f(xb[(int64_t)row * N + col]);
        }
      }
    }
  } else {
    u16* Cb = (u16*)Cptr + (int64_t)b * Cbs;
#pragma unroll
    for (int m = 0; m < 4; ++m) {
#pragma unroll
      for (int r = 0; r < 4; ++r) {
        const int row = r0 + m * 16 + r;
        float a1 = 0.f, a3 = 0.f;
        if (EPI == 6) { a1 = v1[b512 + row]; a3 = v3[row]; }
#pragma unroll
        for (int n = 0; n < 4; ++n) {
          const int col = c0 + n * 16;
          float v = acc[m][n][r];
          if (EPI == 6) v += a1 * v2[col] + a3 * v4[b512 + col];
          Cb[(int64_t)row * N + col] = f2bf(v);
        }
      }
    }
  }
}

// ---- f32 row -> bf16 row + row-sum (x only).  One block per row. ----
__global__ void cvt_row(const float* __restrict__ in, u16* __restrict__ out,
                        float* __restrict__ rowsum) {
  const int64_t row = blockIdx.x;
  const float4* ib = (const float4*)(in + row * 1152);
  U16x4* ob = (U16x4*)(out + row * 1152);
  float s = 0.f;
  for (int i = threadIdx.x; i < 288; i += 256) {
    float4 v = ib[i];
    s += v.x + v.y + v.z + v.w;
    U16x4 o = {f2bf(v.x), f2bf(v.y), f2bf(v.z), f2bf(v.w)};
    ob[i] = o;
  }
  s = wave_red(s);
  __shared__ float red[4];
  if ((threadIdx.x & 63) == 0) red[threadIdx.x >> 6] = s;
  __syncthreads();
  if (threadIdx.x == 0) rowsum[row] = red[0] + red[1] + red[2] + red[3];
}

// ---- x_h: f32 [C][N] -> bf16 [C][N] + bf16 [N][C] + partial rowsums ----
__global__ void prep_xh(const float* __restrict__ xh, u16* __restrict__ xhB,
                        u16* __restrict__ xhT, float* __restrict__ rxh_part) {
  __shared__ float tl[32][33];
  const int b = blockIdx.z;
  const int n0 = blockIdx.x * 32, c0 = blockIdx.y * 32;
  const float* ib = xh + (int64_t)b * 589824;
  const int tr = threadIdx.x >> 3, tc = (threadIdx.x & 7) * 4;
  const float4 v = *(const float4*)&ib[(int64_t)(c0 + tr) * 1152 + n0 + tc];
  tl[tr][tc] = v.x; tl[tr][tc + 1] = v.y; tl[tr][tc + 2] = v.z; tl[tr][tc + 3] = v.w;
  U16x4 o = {f2bf(v.x), f2bf(v.y), f2bf(v.z), f2bf(v.w)};
  *(U16x4*)&xhB[(int64_t)b * 589824 + (int64_t)(c0 + tr) * 1152 + n0 + tc] = o;
  __syncthreads();
  U16x4 ot = {f2bf(tl[tc][tr]), f2bf(tl[tc + 1][tr]),
              f2bf(tl[tc + 2][tr]), f2bf(tl[tc + 3][tr])};
  *(U16x4*)&xhT[(int64_t)b * 589824 + (int64_t)(n0 + tr) * 512 + c0 + tc] = ot;
  if (threadIdx.x < 32) {
    float s = 0;
#pragma unroll
    for (int c = 0; c < 32; ++c) s += tl[threadIdx.x][c];
    rxh_part[(n0 >> 5) * 16384 + b * 512 + c0 + threadIdx.x] = s;
  }
}

// ---- 4x fused 512x512 f32 -> bf16 transpose (blockIdx.z selects weight) ----
__global__ void transpose_cvt4(const float* __restrict__ s0, const float* __restrict__ s1,
                               const float* __restrict__ s2, const float* __restrict__ s3,
                               u16* __restrict__ d0, u16* __restrict__ d1,
                               u16* __restrict__ d2, u16* __restrict__ d3) {
  const int z = blockIdx.z;
  const float* in = z == 0 ? s0 : z == 1 ? s1 : z == 2 ? s2 : s3;
  u16* out = z == 0 ? d0 : z == 1 ? d1 : z == 2 ? d2 : d3;
  __shared__ float t[32][33];
  const int n0 = blockIdx.x * 32, c0 = blockIdx.y * 32;
  const int tr = threadIdx.x >> 3, tc = (threadIdx.x & 7) * 4;
  const float4 v = *(const float4*)&in[(int64_t)(c0 + tr) * 512 + n0 + tc];
  t[tr][tc] = v.x; t[tr][tc + 1] = v.y; t[tr][tc + 2] = v.z; t[tr][tc + 3] = v.w;
  __syncthreads();
  U16x4 o;
  o.x = f2bf(t[tc][tr]); o.y = f2bf(t[tc + 1][tr]);
  o.z = f2bf(t[tc + 2][tr]); o.w = f2bf(t[tc + 3][tr]);
  *(U16x4*)&out[(int64_t)(n0 + tr) * 512 + c0 + tc] = o;
}

// ---- f32 -> bf16 elementwise ----
__global__ void cvt_kernel(const float* __restrict__ in, u16* __restrict__ out, int n4) {
  const int i = blockIdx.x * 256 + threadIdx.x;
  if (i < n4) {
    const float4 v = ((const float4*)in)[i];
    U16x4 o = {f2bf(v.x), f2bf(v.y), f2bf(v.z), f2bf(v.w)};
    ((U16x4*)out)[i] = o;
  }
}

// ---- micro: rxh reduce (blocks 0..63) + BN prep + s2 (block 64) ----
__global__ void k_misc(const float* __restrict__ rxh_part, float* __restrict__ rxh,
                       const float* __restrict__ gamma, const float* __restrict__ beta,
                       const float* __restrict__ mean, const float* __restrict__ var,
                       const float* __restrict__ bw,
                       const float* __restrict__ bp, const float* __restrict__ bg,
                       float* __restrict__ sc2, float* __restrict__ shift0,
                       float* __restrict__ s2) {
  if (blockIdx.x < 64) {
    const int i = blockIdx.x * 256 + threadIdx.x;   // i = b*512 + c
    float s = 0;
#pragma unroll 4
    for (int p = 0; p < 36; ++p) s += rxh_part[p * 16384 + i];
    rxh[i] = s;
  } else {
    for (int c = threadIdx.x; c < 512; c += 256) {
      const float sc = gamma[c] * rsqrtf(var[c] + 1e-5f);
      sc2[c] = sc * (1.0f / 512.0f);
      shift0[c] = (bw[c] - mean[c]) * sc + beta[c];
    }
    if (threadIdx.x < 64) {
      float p = 0;
      for (int k = threadIdx.x; k < 512; k += 64) p += bp[k] * bg[k];
      p = wave_red(p);
      if (threadIdx.x == 0) s2[0] = p;
    }
  }
}

// ---- wave-per-row matvecs, stage 1: sigphi, tau2, h1, w1, c2 ----
__global__ void k_mv1(const float* __restrict__ Wp, const float* __restrict__ Wt,
                      const float* __restrict__ Ww,
                      const u16* __restrict__ WpT, const u16* __restrict__ WgT,
                      const float* __restrict__ bg, const float* __restrict__ bt,
                      const float* __restrict__ bp,
                      const float* __restrict__ rx, const float* __restrict__ rxh,
                      float* __restrict__ sigphi, float* __restrict__ tau2,
                      float* __restrict__ h1, float* __restrict__ w1,
                      float* __restrict__ c2) {
  const int wid = blockIdx.x * 4 + (threadIdx.x >> 6);
  const int lane = threadIdx.x & 63;
  float dot = 0;
  if (wid < 16384) {                     // sigphi[b,t] = Wp[t,:].rxh[b,:]
    const int b = wid >> 9, t = wid & 511;
    const float* wr = Wp + (int64_t)t * 512;
    const float* vr = rxh + b * 512;
#pragma unroll
    for (int k = 0; k < 8; ++k) dot += wr[lane + k * 64] * vr[lane + k * 64];
    dot = wave_red(dot);
    if (lane == 0) sigphi[wid] = dot;
  } else if (wid < 32768) {              // tau2[b,t] = Wt[t,:].rx[b,:] + 1152 bt[t]
    const int r = wid - 16384, b = r >> 9, t = r & 511;
    const float* wr = Wt + (int64_t)t * 512;
    const float* vr = rx + b * 512;
#pragma unroll
    for (int k = 0; k < 8; ++k) dot += wr[lane + k * 64] * vr[lane + k * 64];
    dot = wave_red(dot);
    if (lane == 0) tau2[r] = dot + 1152.0f * bt[t];
  } else if (wid < 33280) {              // h1[j] = WpT[j,:].bg
    const int j = wid - 32768;
    const u16* wr = WpT + (int64_t)j * 512;
#pragma unroll
    for (int k = 0; k < 8; ++k) dot += bf2f(wr[lane + k * 64]) * bg[lane + k * 64];
    dot = wave_red(dot);
    if (lane == 0) h1[j] = dot;
  } else if (wid < 33792) {              // w1[c] = Ww[c,:].bt
    const int c = wid - 33280;
    const float* wr = Ww + (int64_t)c * 512;
#pragma unroll
    for (int k = 0; k < 8; ++k) dot += wr[lane + k * 64] * bt[lane + k * 64];
    dot = wave_red(dot);
    if (lane == 0) w1[c] = dot;
  } else {                               // c2[e] = WgT[e,:].bp
    const int e = wid - 33792;
    const u16* wr = WgT + (int64_t)e * 512;
#pragma unroll
    for (int k = 0; k < 8; ++k) dot += bf2f(wr[lane + k * 64]) * bp[lane + k * 64];
    dot = wave_red(dot);
    if (lane == 0) c2[e] = dot;
  }
}

// ---- wave-per-row matvecs, stage 2: c1, w2, s1 ----
__global__ void k_mv2(const u16* __restrict__ WgT, const float* __restrict__ Ww,
                      const float* __restrict__ bg,
                      const float* __restrict__ sigphi, const float* __restrict__ tau2,
                      float* __restrict__ c1, float* __restrict__ w2,
                      float* __restrict__ s1) {
  const int wid = blockIdx.x * 4 + (threadIdx.x >> 6);
  const int lane = threadIdx.x & 63;
  float dot = 0;
  if (wid < 16384) {                     // c1[b,t] = WgT[t,:].sigphi[b,:]
    const int b = wid >> 9, t = wid & 511;
    const u16* wr = WgT + (int64_t)t * 512;
    const float* vr = sigphi + b * 512;
#pragma unroll
    for (int k = 0; k < 8; ++k) dot += bf2f(wr[lane + k * 64]) * vr[lane + k * 64];
    dot = wave_red(dot);
    if (lane == 0) c1[wid] = dot;
  } else if (wid < 32768) {              // w2[b,t] = Ww[t,:].tau2[b,:]
    const int r = wid - 16384, b = r >> 9, t = r & 511;
    const float* wr = Ww + (int64_t)t * 512;
    const float* vr = tau2 + b * 512;
#pragma unroll
    for (int k = 0; k < 8; ++k) dot += wr[lane + k * 64] * vr[lane + k * 64];
    dot = wave_red(dot);
    if (lane == 0) w2[r] = dot;
  } else if (wid < 32800) {              // s1[b] = sigphi[b,:].bg
    const int b = wid - 32768;
    const float* vr = sigphi + b * 512;
#pragma unroll
    for (int k = 0; k < 8; ++k) dot += vr[lane + k * 64] * bg[lane + k * 64];
    dot = wave_red(dot);
    if (lane == 0) s1[b] = dot;
  }
}

// ---- shiftv[b,c] = sc2[c]*(R[b][c,:].h1 + s1[b]w1[c] + s2*w2[b,c]) + shift0[c]
__global__ void k_shiftv(const u16* __restrict__ R, const float* __restrict__ h1,
                         const float* __restrict__ w1, const float* __restrict__ w2,
                         const float* __restrict__ s1, const float* __restrict__ s2,
                         const float* __restrict__ sc2, const float* __restrict__ shift0,
                         float* __restrict__ shiftv) {
  const int wid = blockIdx.x * 4 + (threadIdx.x >> 6);
  const int lane = threadIdx.x & 63;
  const int b = wid >> 9, c = wid & 511;
  const u16* rr = R + (int64_t)b * 262144 + (int64_t)c * 512;
  float dot = 0;
#pragma unroll
  for (int k = 0; k < 8; ++k) dot += bf2f(rr[lane + k * 64]) * h1[lane + k * 64];
  dot = wave_red(dot);
  if (lane == 0)
    shiftv[wid] = sc2[c] * (dot + s1[b] * w1[c] + s2[0] * w2[wid]) + shift0[c];
}

extern "C" void kernel_launch(void* const* d_in, const int* in_sizes, int n_in,
                              void* d_out, int out_size, void* d_ws, size_t ws_size,
                              hipStream_t stream) {
  const float* x     = (const float*)d_in[0];
  const float* x_h   = (const float*)d_in[1];
  const float* Wg    = (const float*)d_in[2];
  const float* bg    = (const float*)d_in[3];
  const float* Wt    = (const float*)d_in[4];
  const float* bt    = (const float*)d_in[5];
  const float* Wp    = (const float*)d_in[6];
  const float* bp    = (const float*)d_in[7];
  const float* Ww    = (const float*)d_in[8];
  const float* bw    = (const float*)d_in[9];
  const float* gamma = (const float*)d_in[10];
  const float* beta  = (const float*)d_in[11];
  const float* rmean = (const float*)d_in[12];
  const float* rvar  = (const float*)d_in[13];
  float* out = (float*)d_out;

  const int Bsz = 32, D = 512, N = 1152;
  const int64_t DN = (int64_t)D * N;   // 589824
  const int64_t DD = (int64_t)D * D;   // 262144

  char* ws = (char*)d_ws;
  const size_t KB = 1024, MB = 1048576;
  u16* WtT  = (u16*)(ws + 0);            // pair B: [WtT, WpT]
  u16* WpT  = (u16*)(ws + 512 * KB);
  u16* WwB  = (u16*)(ws + 1 * MB);       // pair A: [WwB, WgT]
  u16* WgT  = (u16*)(ws + 1 * MB + 512 * KB);
  u16* WaB  = (u16*)(ws + 2 * MB);       // pair C: [Wa, WbT]
  u16* WbTB = (u16*)(ws + 2 * MB + 512 * KB);
  u16* WwT  = (u16*)(ws + 3 * MB);
  float* rx     = (float*)(ws + 3 * MB + 512 * KB);
  float* rxh    = (float*)(ws + 3 * MB + 576 * KB);
  float* sigphi = (float*)(ws + 3 * MB + 640 * KB);
  float* tau2   = (float*)(ws + 3 * MB + 704 * KB);
  float* c1     = (float*)(ws + 3 * MB + 768 * KB);
  float* w2     = (float*)(ws + 3 * MB + 832 * KB);
  float* shiftv = (float*)(ws + 3 * MB + 896 * KB);
  float* h1     = (float*)(ws + 3 * MB + 960 * KB);
  float* w1     = (float*)(ws + 3 * MB + 962 * KB);
  float* c2     = (float*)(ws + 3 * MB + 964 * KB);
  float* sc2    = (float*)(ws + 3 * MB + 968 * KB);
  float* shift0 = (float*)(ws + 3 * MB + 970 * KB);
  float* s1     = (float*)(ws + 3 * MB + 972 * KB);
  float* s2     = (float*)(ws + 3 * MB + 974 * KB);
  u16* xB  = (u16*)(ws + 4 * MB);                  // 36 MB
  u16* xhB = (u16*)(ws + 40 * MB);                 // 36 MB
  u16* xhT = (u16*)(ws + 76 * MB);                 // 36 MB
  u16* SD1 = (u16*)(ws + 112 * MB);                // 17 MB (MT -> Q)
  u16* SD2 = (u16*)(ws + 130 * MB);                // 17 MB (R)
  float* rxh_part = (float*)(ws + 148 * MB);       // 2.25 MB

  // --- prep ---
  cvt_row<<<dim3(Bsz * D), 256, 0, stream>>>(x, xB, rx);
  prep_xh<<<dim3(36, 16, Bsz), 256, 0, stream>>>(x_h, xhB, xhT, rxh_part);
  transpose_cvt4<<<dim3(16, 16, 4), 256, 0, stream>>>(Wt, Wp, Wg, Ww, WtT, WpT, WgT, WwT);
  cvt_kernel<<<dim3(D * D / 4 / 256), 256, 0, stream>>>(Ww, WwB, D * D / 4);
  k_misc<<<dim3(65), 256, 0, stream>>>(rxh_part, rxh, gamma, beta, rmean, rvar, bw,
                                       bp, bg, sc2, shift0, s2);
  k_mv1<<<dim3(8576), 256, 0, stream>>>(Wp, Wt, Ww, WpT, WgT, bg, bt, bp, rx, rxh,
                                        sigphi, tau2, h1, w1, c2);
  k_mv2<<<dim3(8200), 256, 0, stream>>>(WgT, Ww, bg, sigphi, tau2, c1, w2, s1);
  // Wa = Ww*Wt (b=0) ; WbT[e,j] = sum_k Wg[k,e]Wp[k,j] (b=1) — one dispatch
  gemm_abt<0><<<dim3(4, 2, 2), 512, 0, stream>>>(
      WwB, DD, WtT, DD, WaB, DD, D, D, D, nullptr, nullptr, nullptr, nullptr, nullptr);

  // --- main chain (flat grids, XCD-batch swizzled) ---
  // G1: MT[j,i] = sum_n x_h[j,n] x[i,n]
  gemm_abt<0><<<dim3(8 * Bsz), 512, 0, stream>>>(
      xhB, DN, xB, DN, SD1, DD, D, D, N, nullptr, nullptr, nullptr, nullptr, nullptr);
  // G2: R[p,j] = sum_i Wa[p,i] MT[j,i]
  gemm_abt<0><<<dim3(8 * Bsz), 512, 0, stream>>>(
      WaB, 0, SD1, DD, SD2, DD, D, D, D, nullptr, nullptr, nullptr, nullptr, nullptr);
  // shiftv = sc2*(R.h1 + s1*w1 + s2*w2) + shift0
  k_shiftv<<<dim3(4096), 256, 0, stream>>>(SD2, h1, w1, w2, s1, s2, sc2, shift0, shiftv);
  // G3: Q[p,e] = sum_j R[p,j] WbT[e,j] + rank-2 bias correction
  gemm_abt<6><<<dim3(8 * Bsz), 512, 0, stream>>>(
      SD2, DD, WbTB, 0, SD1, DD, D, D, D, w2, c2, w1, c1, nullptr);
  // G6: out[c,n] = sc2[c]*sum_e Q[c,e] xhT[n,e] + shiftv[b,c] + xB[b,c,n]
  gemm_abt<4><<<dim3(18 * Bsz), 512, 0, stream>>>(
      SD1, DD, xhT, DN, out, DN, D, N, D, sc2, shiftv, nullptr, nullptr, xB);
}

// Round 9
// 208.205 us; speedup vs baseline: 1.0815x; 1.0815x over previous
//
#include <hip/hip_runtime.h>
#include <stdint.h>

typedef short short8 __attribute__((ext_vector_type(8)));
typedef float f32x4 __attribute__((ext_vector_type(4)));
typedef unsigned short u16;
typedef unsigned int u32;

struct alignas(8) U16x4 { u16 x, y, z, w; };

__device__ __forceinline__ u16 f2bf(float f) {
  u32 u = __float_as_uint(f);
  u += 0x7fffu + ((u >> 16) & 1u);
  return (u16)(u >> 16);
}
__device__ __forceinline__ float bf2f(u16 v) {
  return __uint_as_float(((u32)v) << 16);
}

__device__ __forceinline__ void gld_lds16(const u16* g, u16* l) {
  __builtin_amdgcn_global_load_lds((const __attribute__((address_space(1))) u32*)g,
                                   (__attribute__((address_space(3))) u32*)l,
                                   16, 0, 0);
}

__device__ __forceinline__ void mfma16x16x32(f32x4& c, short8 a, short8 b) {
  asm("v_mfma_f32_16x16x32_bf16 %0, %1, %2, %0" : "+v"(c) : "v"(a), "v"(b));
}

__device__ __forceinline__ float wave_red(float v) {
  for (int off = 32; off; off >>= 1) v += __shfl_down(v, off);
  return v;
}

// ---------------------------------------------------------------------------
// Batched C = A * B^T (A:[M,K] rm, Bt:[N,K] rm). BM=256 x BN=128 x BK=32,
// 512 threads / 8 waves (4x2, wave tile 64x64, acc[4][4]).
// 3-DEEP PREFETCH RING: 4 LDS buffers (96 KB dynamic), loop =
//   barrier; stage(t+3); vmcnt(9); barrier; MFMA   (tail drains 6/3/0)
// so each tile's loads have 3 full iterations to land — hides L2/L3/HBM
// latency even at 1 block/CU (the measured 8 B/cyc/CU staging wall).
// T2: XOR-swizzle (16B chunk ^= row&3); linear LDS dest, pre-swizzled global
//     source (rule #21).  T1: flat grids decode batch b onto XCD b%8.
// T5: setprio(1) around the MFMA cluster.
// EPI 0: bf16 out; EPI 6: bf16 + v1[b512+row]*v2[col] + v3[row]*v4[b512+col];
// EPI 4: f32 out, acc*v1[row] + v2[b512+row] + bf16 xres[b][row][col]
// Requires nt = K/32 >= 3 (K >= 96).
// ---------------------------------------------------------------------------
template<int EPI>
__global__ void __launch_bounds__(512, 2) gemm_abt(
                         const u16* __restrict__ A, int64_t Abs,
                         const u16* __restrict__ Bt, int64_t Bbs,
                         void* __restrict__ Cptr, int64_t Cbs,
                         int M, int N, int K,
                         const float* __restrict__ v1,
                         const float* __restrict__ v2,
                         const float* __restrict__ v3,
                         const float* __restrict__ v4,
                         const u16* __restrict__ xres) {
  constexpr int BM = 256, BN = 128, BK = 32;
  extern __shared__ u16 lds[];          // As: 4 x 8192 elems, Bs: 4 x 4096
  u16* ldsA = lds;
  u16* ldsB = lds + 4 * (BM * BK);

  int bx, by, b;
  if (gridDim.z == 1) {            // T1: XCD-aware flat decode
    const int nbx = N >> 7;
    const int bpb = nbx * (M >> 8);
    const int id = blockIdx.x;
    const int xcd = id & 7, rest = id >> 3;
    b = xcd + 8 * (rest / bpb);
    const int wi = rest % bpb;
    by = wi / nbx; bx = wi % nbx;
  } else {
    bx = blockIdx.x; by = blockIdx.y; b = blockIdx.z;
  }

  const u16* Ab = A + (int64_t)b * Abs;
  const u16* Bb = Bt + (int64_t)b * Bbs;
  const int brow = by * BM, bcol = bx * BN;
  const int tid = threadIdx.x, lane = tid & 63, w = tid >> 6;
  const int wr = w >> 1, wc = w & 1;  // 4x2 wave grid; wave tile 64x64

  f32x4 acc[4][4] = {};

  // staging: thread t -> row sr=t>>2 (A also sr+128), 8-elem chunk t&3.
  // LDS dest LINEAR; global chunk pre-swizzled ^(row&3)  (rule #21).
  const int sr = tid >> 2;           // 0..127
  const int scs = ((tid & 3) ^ (sr & 3)) * 8;
  const int lo = sr * BK + (tid & 3) * 8;   // per-thread LDS offset within buf
  const u16* gA = Ab + (int64_t)(brow + sr) * K + scs;
  const u16* gB = Bb + (int64_t)(bcol + sr) * K + scs;

  const int la16 = lane & 15;
  const int kg = (lane >> 4) * 8;            // k-granule 0/8/16/24
  const int kc = kg ^ ((la16 & 3) * 8);      // swizzled ds_read chunk
  const int nt = K / BK;

#define STAGE(buf, k0)                                              \
  do {                                                              \
    u16* la_ = ldsA + (buf) * (BM * BK) + lo;                       \
    u16* lb_ = ldsB + (buf) * (BN * BK) + lo;                       \
    gld_lds16(gA + (k0), la_);                                      \
    gld_lds16(gA + (int64_t)128 * K + (k0), la_ + 128 * BK);        \
    gld_lds16(gB + (k0), lb_);                                      \
  } while (0)

  // prologue: stage tiles 0,1,2 (9 loads/thread in flight)
  STAGE(0, 0);
  STAGE(1, BK);
  STAGE(2, 2 * BK);

  for (int t = 0; t < nt; ++t) {
    __builtin_amdgcn_s_barrier();  // all waves done reading buf (t-1)&3
    if (t + 3 < nt) {
      STAGE((t + 3) & 3, (t + 3) * BK);
      asm volatile("s_waitcnt vmcnt(9)" ::: "memory");   // tile t landed
    } else {
      const int rem = nt - 1 - t;
      if (rem == 2)      asm volatile("s_waitcnt vmcnt(6)" ::: "memory");
      else if (rem == 1) asm volatile("s_waitcnt vmcnt(3)" ::: "memory");
      else               asm volatile("s_waitcnt vmcnt(0)" ::: "memory");
    }
    __builtin_amdgcn_s_barrier();  // tile t visible to all waves
    __builtin_amdgcn_sched_barrier(0);
    const u16* as = ldsA + (t & 3) * (BM * BK);
    const u16* bs = ldsB + (t & 3) * (BN * BK);
    short8 af[4], bf[4];
#pragma unroll
    for (int m = 0; m < 4; ++m)
      af[m] = *(const short8*)&as[(wr * 64 + m * 16 + la16) * BK + kc];
#pragma unroll
    for (int n = 0; n < 4; ++n)
      bf[n] = *(const short8*)&bs[(wc * 64 + n * 16 + la16) * BK + kc];
    __builtin_amdgcn_s_setprio(1);
#pragma unroll
    for (int m = 0; m < 4; ++m)
#pragma unroll
      for (int n = 0; n < 4; ++n)
        mfma16x16x32(acc[m][n], af[m], bf[n]);
    __builtin_amdgcn_s_setprio(0);
  }
#undef STAGE
  asm volatile("s_nop 7\n\ts_nop 7");  // MFMA->VALU hazard guard

  const int r0 = brow + wr * 64 + (lane >> 4) * 4;
  const int c0 = bcol + wc * 64 + la16;
  const int64_t b512 = (int64_t)b * 512;

  if (EPI == 4) {
    float* Cb = (float*)Cptr + (int64_t)b * Cbs;
    const u16* xb = xres + (int64_t)b * Cbs;
#pragma unroll
    for (int m = 0; m < 4; ++m) {
#pragma unroll
      for (int r = 0; r < 4; ++r) {
        const int row = r0 + m * 16 + r;
        const float scl = v1[row], shf = v2[b512 + row];
#pragma unroll
        for (int n = 0; n < 4; ++n) {
          const int col = c0 + n * 16;
          Cb[(int64_t)row * N + col] =
              acc[m][n][r] * scl + shf + bf2f(xb[(int64_t)row * N + col]);
        }
      }
    }
  } else {
    u16* Cb = (u16*)Cptr + (int64_t)b * Cbs;
#pragma unroll
    for (int m = 0; m < 4; ++m) {
#pragma unroll
      for (int r = 0; r < 4; ++r) {
        const int row = r0 + m * 16 + r;
        float a1 = 0.f, a3 = 0.f;
        if (EPI == 6) { a1 = v1[b512 + row]; a3 = v3[row]; }
#pragma unroll
        for (int n = 0; n < 4; ++n) {
          const int col = c0 + n * 16;
          float v = acc[m][n][r];
          if (EPI == 6) v += a1 * v2[col] + a3 * v4[b512 + col];
          Cb[(int64_t)row * N + col] = f2bf(v);
        }
      }
    }
  }
}

// ---------------------------------------------------------------------------
// prep_all: one pass over BOTH x and x_h, 64x64 tiles.
//  z<32: x batch z    -> xB bf16 [c][n] + rx partial rowsums
//  z>=32: x_h batch z-32 -> xhB + xhT (transpose via LDS) + rxh partials
// grid (18, 8, 64) x 256 thr
// ---------------------------------------------------------------------------
__global__ void prep_all(const float* __restrict__ x, const float* __restrict__ xh,
                         u16* __restrict__ xB, u16* __restrict__ xhB,
                         u16* __restrict__ xhT,
                         float* __restrict__ rx_part, float* __restrict__ rxh_part) {
  __shared__ float tl[64][65];
  __shared__ float rs[64];
  const int z = blockIdx.z;
  const int b = z & 31;
  const bool isxh = z >= 32;
  const float* src = (isxh ? xh : x) + (int64_t)b * 589824;
  u16* dstB = (isxh ? xhB : xB) + (int64_t)b * 589824;
  const int n0 = blockIdx.x * 64, c0 = blockIdx.y * 64;
  const int t = threadIdx.x;
  const int cl = t >> 4;       // row-in-pass 0..15
  const int q = t & 15;        // float4 column
#pragma unroll
  for (int p = 0; p < 4; ++p) {
    const int row = p * 16 + cl;      // c within tile
    const float4 v = *(const float4*)&src[(int64_t)(c0 + row) * 1152 + n0 + q * 4];
    tl[row][q * 4] = v.x; tl[row][q * 4 + 1] = v.y;
    tl[row][q * 4 + 2] = v.z; tl[row][q * 4 + 3] = v.w;
    U16x4 o = {f2bf(v.x), f2bf(v.y), f2bf(v.z), f2bf(v.w)};
    *(U16x4*)&dstB[(int64_t)(c0 + row) * 1152 + n0 + q * 4] = o;
    float pr = v.x + v.y + v.z + v.w;
    pr += __shfl_down(pr, 8); pr += __shfl_down(pr, 4);
    pr += __shfl_down(pr, 2); pr += __shfl_down(pr, 1);
    if (q == 0) rs[row] = pr;
  }
  __syncthreads();
  if (t < 64) {
    float* part = isxh ? rxh_part : rx_part;
    part[blockIdx.x * 16384 + b * 512 + c0 + t] = rs[t];
  }
  if (isxh) {
    const int n = t >> 2, cb = (t & 3) * 16;
    u16* dT = xhT + (int64_t)b * 589824 + (int64_t)(n0 + n) * 512 + c0 + cb;
#pragma unroll
    for (int j = 0; j < 4; ++j) {
      U16x4 o = {f2bf(tl[cb + 4 * j][n]), f2bf(tl[cb + 4 * j + 1][n]),
                 f2bf(tl[cb + 4 * j + 2][n]), f2bf(tl[cb + 4 * j + 3][n])};
      *(U16x4*)&dT[4 * j] = o;
    }
  }
}

// ---- 4x fused 512x512 f32 -> bf16 transpose (blockIdx.z selects weight) ----
__global__ void transpose_cvt4(const float* __restrict__ s0, const float* __restrict__ s1,
                               const float* __restrict__ s2, const float* __restrict__ s3,
                               u16* __restrict__ d0, u16* __restrict__ d1,
                               u16* __restrict__ d2, u16* __restrict__ d3) {
  const int z = blockIdx.z;
  const float* in = z == 0 ? s0 : z == 1 ? s1 : z == 2 ? s2 : s3;
  u16* out = z == 0 ? d0 : z == 1 ? d1 : z == 2 ? d2 : d3;
  __shared__ float t[32][33];
  const int n0 = blockIdx.x * 32, c0 = blockIdx.y * 32;
  const int tr = threadIdx.x >> 3, tc = (threadIdx.x & 7) * 4;
  const float4 v = *(const float4*)&in[(int64_t)(c0 + tr) * 512 + n0 + tc];
  t[tr][tc] = v.x; t[tr][tc + 1] = v.y; t[tr][tc + 2] = v.z; t[tr][tc + 3] = v.w;
  __syncthreads();
  U16x4 o;
  o.x = f2bf(t[tc][tr]); o.y = f2bf(t[tc + 1][tr]);
  o.z = f2bf(t[tc + 2][tr]); o.w = f2bf(t[tc + 3][tr]);
  *(U16x4*)&out[(int64_t)(n0 + tr) * 512 + c0 + tc] = o;
}

// ---- f32 -> bf16 elementwise ----
__global__ void cvt_kernel(const float* __restrict__ in, u16* __restrict__ out, int n4) {
  const int i = blockIdx.x * 256 + threadIdx.x;
  if (i < n4) {
    const float4 v = ((const float4*)in)[i];
    U16x4 o = {f2bf(v.x), f2bf(v.y), f2bf(v.z), f2bf(v.w)};
    ((U16x4*)out)[i] = o;
  }
}

// ---- micro: rxh reduce (0..63), rx reduce (64..127), BN prep + s2 (128) ----
__global__ void k_misc(const float* __restrict__ rx_part, const float* __restrict__ rxh_part,
                       float* __restrict__ rx, float* __restrict__ rxh,
                       const float* __restrict__ gamma, const float* __restrict__ beta,
                       const float* __restrict__ mean, const float* __restrict__ var,
                       const float* __restrict__ bw,
                       const float* __restrict__ bp, const float* __restrict__ bg,
                       float* __restrict__ sc2, float* __restrict__ shift0,
                       float* __restrict__ s2) {
  if (blockIdx.x < 64) {
    const int i = blockIdx.x * 256 + threadIdx.x;
    float s = 0;
#pragma unroll 3
    for (int p = 0; p < 18; ++p) s += rxh_part[p * 16384 + i];
    rxh[i] = s;
  } else if (blockIdx.x < 128) {
    const int i = (blockIdx.x - 64) * 256 + threadIdx.x;
    float s = 0;
#pragma unroll 3
    for (int p = 0; p < 18; ++p) s += rx_part[p * 16384 + i];
    rx[i] = s;
  } else {
    for (int c = threadIdx.x; c < 512; c += 256) {
      const float sc = gamma[c] * rsqrtf(var[c] + 1e-5f);
      sc2[c] = sc * (1.0f / 512.0f);
      shift0[c] = (bw[c] - mean[c]) * sc + beta[c];
    }
    if (threadIdx.x < 64) {
      float p = 0;
      for (int k = threadIdx.x; k < 512; k += 64) p += bp[k] * bg[k];
      p = wave_red(p);
      if (threadIdx.x == 0) s2[0] = p;
    }
  }
}

// ---- wave-per-row matvecs, stage 1: sigphi, tau2, h1, w1, c2 ----
__global__ void k_mv1(const float* __restrict__ Wp, const float* __restrict__ Wt,
                      const float* __restrict__ Ww,
                      const u16* __restrict__ WpT, const u16* __restrict__ WgT,
                      const float* __restrict__ bg, const float* __restrict__ bt,
                      const float* __restrict__ bp,
                      const float* __restrict__ rx, const float* __restrict__ rxh,
                      float* __restrict__ sigphi, float* __restrict__ tau2,
                      float* __restrict__ h1, float* __restrict__ w1,
                      float* __restrict__ c2) {
  const int wid = blockIdx.x * 4 + (threadIdx.x >> 6);
  const int lane = threadIdx.x & 63;
  float dot = 0;
  if (wid < 16384) {                     // sigphi[b,t] = Wp[t,:].rxh[b,:]
    const int b = wid >> 9, t = wid & 511;
    const float* wr = Wp + (int64_t)t * 512;
    const float* vr = rxh + b * 512;
#pragma unroll
    for (int k = 0; k < 8; ++k) dot += wr[lane + k * 64] * vr[lane + k * 64];
    dot = wave_red(dot);
    if (lane == 0) sigphi[wid] = dot;
  } else if (wid < 32768) {              // tau2[b,t] = Wt[t,:].rx[b,:] + 1152 bt[t]
    const int r = wid - 16384, b = r >> 9, t = r & 511;
    const float* wr = Wt + (int64_t)t * 512;
    const float* vr = rx + b * 512;
#pragma unroll
    for (int k = 0; k < 8; ++k) dot += wr[lane + k * 64] * vr[lane + k * 64];
    dot = wave_red(dot);
    if (lane == 0) tau2[r] = dot + 1152.0f * bt[t];
  } else if (wid < 33280) {              // h1[j] = WpT[j,:].bg
    const int j = wid - 32768;
    const u16* wr = WpT + (int64_t)j * 512;
#pragma unroll
    for (int k = 0; k < 8; ++k) dot += bf2f(wr[lane + k * 64]) * bg[lane + k * 64];
    dot = wave_red(dot);
    if (lane == 0) h1[j] = dot;
  } else if (wid < 33792) {              // w1[c] = Ww[c,:].bt
    const int c = wid - 33280;
    const float* wr = Ww + (int64_t)c * 512;
#pragma unroll
    for (int k = 0; k < 8; ++k) dot += wr[lane + k * 64] * bt[lane + k * 64];
    dot = wave_red(dot);
    if (lane == 0) w1[c] = dot;
  } else {                               // c2[e] = WgT[e,:].bp
    const int e = wid - 33792;
    const u16* wr = WgT + (int64_t)e * 512;
#pragma unroll
    for (int k = 0; k < 8; ++k) dot += bf2f(wr[lane + k * 64]) * bp[lane + k * 64];
    dot = wave_red(dot);
    if (lane == 0) c2[e] = dot;
  }
}

// ---- wave-per-row matvecs, stage 2: c1, w2, s1 ----
__global__ void k_mv2(const u16* __restrict__ WgT, const float* __restrict__ Ww,
                      const float* __restrict__ bg,
                      const float* __restrict__ sigphi, const float* __restrict__ tau2,
                      float* __restrict__ c1, float* __restrict__ w2,
                      float* __restrict__ s1) {
  const int wid = blockIdx.x * 4 + (threadIdx.x >> 6);
  const int lane = threadIdx.x & 63;
  float dot = 0;
  if (wid < 16384) {                     // c1[b,t] = WgT[t,:].sigphi[b,:]
    const int b = wid >> 9, t = wid & 511;
    const u16* wr = WgT + (int64_t)t * 512;
    const float* vr = sigphi + b * 512;
#pragma unroll
    for (int k = 0; k < 8; ++k) dot += bf2f(wr[lane + k * 64]) * vr[lane + k * 64];
    dot = wave_red(dot);
    if (lane == 0) c1[wid] = dot;
  } else if (wid < 32768) {              // w2[b,t] = Ww[t,:].tau2[b,:]
    const int r = wid - 16384, b = r >> 9, t = r & 511;
    const float* wr = Ww + (int64_t)t * 512;
    const float* vr = tau2 + b * 512;
#pragma unroll
    for (int k = 0; k < 8; ++k) dot += wr[lane + k * 64] * vr[lane + k * 64];
    dot = wave_red(dot);
    if (lane == 0) w2[r] = dot;
  } else if (wid < 32800) {              // s1[b] = sigphi[b,:].bg
    const int b = wid - 32768;
    const float* vr = sigphi + b * 512;
#pragma unroll
    for (int k = 0; k < 8; ++k) dot += vr[lane + k * 64] * bg[lane + k * 64];
    dot = wave_red(dot);
    if (lane == 0) s1[b] = dot;
  }
}

// ---- shiftv[b,c] = sc2[c]*(R[b][c,:].h1 + s1[b]w1[c] + s2*w2[b,c]) + shift0[c]
__global__ void k_shiftv(const u16* __restrict__ R, const float* __restrict__ h1,
                         const float* __restrict__ w1, const float* __restrict__ w2,
                         const float* __restrict__ s1, const float* __restrict__ s2,
                         const float* __restrict__ sc2, const float* __restrict__ shift0,
                         float* __restrict__ shiftv) {
  const int wid = blockIdx.x * 4 + (threadIdx.x >> 6);
  const int lane = threadIdx.x & 63;
  const int b = wid >> 9, c = wid & 511;
  const u16* rr = R + (int64_t)b * 262144 + (int64_t)c * 512;
  float dot = 0;
#pragma unroll
  for (int k = 0; k < 8; ++k) dot += bf2f(rr[lane + k * 64]) * h1[lane + k * 64];
  dot = wave_red(dot);
  if (lane == 0)
    shiftv[wid] = sc2[c] * (dot + s1[b] * w1[c] + s2[0] * w2[wid]) + shift0[c];
}

extern "C" void kernel_launch(void* const* d_in, const int* in_sizes, int n_in,
                              void* d_out, int out_size, void* d_ws, size_t ws_size,
                              hipStream_t stream) {
  const float* x     = (const float*)d_in[0];
  const float* x_h   = (const float*)d_in[1];
  const float* Wg    = (const float*)d_in[2];
  const float* bg    = (const float*)d_in[3];
  const float* Wt    = (const float*)d_in[4];
  const float* bt    = (const float*)d_in[5];
  const float* Wp    = (const float*)d_in[6];
  const float* bp    = (const float*)d_in[7];
  const float* Ww    = (const float*)d_in[8];
  const float* bw    = (const float*)d_in[9];
  const float* gamma = (const float*)d_in[10];
  const float* beta  = (const float*)d_in[11];
  const float* rmean = (const float*)d_in[12];
  const float* rvar  = (const float*)d_in[13];
  float* out = (float*)d_out;

  const int Bsz = 32, D = 512, N = 1152;
  const int64_t DN = (int64_t)D * N;   // 589824
  const int64_t DD = (int64_t)D * D;   // 262144
  const size_t LDSB = 98304;           // 96 KB dynamic LDS for gemm_abt

  char* ws = (char*)d_ws;
  const size_t KB = 1024, MB = 1048576;
  u16* WtT  = (u16*)(ws + 0);            // pair B: [WtT, WpT]
  u16* WpT  = (u16*)(ws + 512 * KB);
  u16* WwB  = (u16*)(ws + 1 * MB);       // pair A: [WwB, WgT]
  u16* WgT  = (u16*)(ws + 1 * MB + 512 * KB);
  u16* WaB  = (u16*)(ws + 2 * MB);       // pair C: [Wa, WbT]
  u16* WbTB = (u16*)(ws + 2 * MB + 512 * KB);
  float* rx     = (float*)(ws + 3 * MB + 512 * KB);
  float* rxh    = (float*)(ws + 3 * MB + 576 * KB);
  float* sigphi = (float*)(ws + 3 * MB + 640 * KB);
  float* tau2   = (float*)(ws + 3 * MB + 704 * KB);
  float* c1     = (float*)(ws + 3 * MB + 768 * KB);
  float* w2     = (float*)(ws + 3 * MB + 832 * KB);
  float* shiftv = (float*)(ws + 3 * MB + 896 * KB);
  float* h1     = (float*)(ws + 3 * MB + 960 * KB);
  float* w1     = (float*)(ws + 3 * MB + 962 * KB);
  float* c2     = (float*)(ws + 3 * MB + 964 * KB);
  float* sc2    = (float*)(ws + 3 * MB + 968 * KB);
  float* shift0 = (float*)(ws + 3 * MB + 970 * KB);
  float* s1     = (float*)(ws + 3 * MB + 972 * KB);
  float* s2     = (float*)(ws + 3 * MB + 974 * KB);
  u16* xB  = (u16*)(ws + 4 * MB);                  // 36 MB
  u16* xhB = (u16*)(ws + 40 * MB);                 // 36 MB
  u16* xhT = (u16*)(ws + 76 * MB);                 // 36 MB
  u16* SD1 = (u16*)(ws + 112 * MB);                // 17 MB (MT -> Q)
  u16* SD2 = (u16*)(ws + 130 * MB);                // 17 MB (R)
  float* rx_part  = (float*)(ws + 148 * MB);       // 18*16384*4 = 1.13 MB
  float* rxh_part = (float*)(ws + 150 * MB);       // 1.13 MB

  // --- prep ---
  prep_all<<<dim3(18, 8, 64), 256, 0, stream>>>(x, x_h, xB, xhB, xhT,
                                                rx_part, rxh_part);
  transpose_cvt4<<<dim3(16, 16, 4), 256, 0, stream>>>(Wt, Wp, Wg, Ww, WtT, WpT, WgT,
                                                      (u16*)(ws + 152 * MB) /*WwT unused*/);
  cvt_kernel<<<dim3(D * D / 4 / 256), 256, 0, stream>>>(Ww, WwB, D * D / 4);
  k_misc<<<dim3(129), 256, 0, stream>>>(rx_part, rxh_part, rx, rxh, gamma, beta,
                                        rmean, rvar, bw, bp, bg, sc2, shift0, s2);
  k_mv1<<<dim3(8576), 256, 0, stream>>>(Wp, Wt, Ww, WpT, WgT, bg, bt, bp, rx, rxh,
                                        sigphi, tau2, h1, w1, c2);
  k_mv2<<<dim3(8200), 256, 0, stream>>>(WgT, Ww, bg, sigphi, tau2, c1, w2, s1);
  // Wa = Ww*Wt (b=0) ; WbT[e,j] = sum_k Wg[k,e]Wp[k,j] (b=1) — one dispatch
  gemm_abt<0><<<dim3(4, 2, 2), 512, LDSB, stream>>>(
      WwB, DD, WtT, DD, WaB, DD, D, D, D, nullptr, nullptr, nullptr, nullptr, nullptr);

  // --- main chain (flat grids, XCD-batch swizzled) ---
  // G1: MT[j,i] = sum_n x_h[j,n] x[i,n]
  gemm_abt<0><<<dim3(8 * Bsz), 512, LDSB, stream>>>(
      xhB, DN, xB, DN, SD1, DD, D, D, N, nullptr, nullptr, nullptr, nullptr, nullptr);
  // G2: R[p,j] = sum_i Wa[p,i] MT[j,i]
  gemm_abt<0><<<dim3(8 * Bsz), 512, LDSB, stream>>>(
      WaB, 0, SD1, DD, SD2, DD, D, D, D, nullptr, nullptr, nullptr, nullptr, nullptr);
  // shiftv = sc2*(R.h1 + s1*w1 + s2*w2) + shift0
  k_shiftv<<<dim3(4096), 256, 0, stream>>>(SD2, h1, w1, w2, s1, s2, sc2, shift0, shiftv);
  // G3: Q[p,e] = sum_j R[p,j] WbT[e,j] + rank-2 bias correction
  gemm_abt<6><<<dim3(8 * Bsz), 512, LDSB, stream>>>(
      SD2, DD, WbTB, 0, SD1, DD, D, D, D, w2, c2, w1, c1, nullptr);
  // G6: out[c,n] = sc2[c]*sum_e Q[c,e] xhT[n,e] + shiftv[b,c] + xB[b,c,n]
  gemm_abt<4><<<dim3(18 * Bsz), 512, LDSB, stream>>>(
      SD1, DD, xhT, DN, out, DN, D, N, D, sc2, shiftv, nullptr, nullptr, xB);
}